// Round 9
// baseline (164.638 us; speedup 1.0000x reference)
//
#include <hip/hip_runtime.h>
#include <math.h>

#define NB 2
#define NO 512
#define NQ 512
#define OUT_DIM 128
#define LPAD 516   // logits row pitch (floats)
#define RPITCH 260 // reduce pitch

typedef __attribute__((ext_vector_type(8))) short short8;   // 8 bf16
typedef __attribute__((ext_vector_type(4))) float f32x4;    // MFMA acc
typedef float v2f __attribute__((ext_vector_type(2)));

__device__ __forceinline__ float softplus_f(float x) {
  return x > 0.0f ? x + log1pf(expf(-x)) : log1pf(expf(x));
}
__device__ __forceinline__ unsigned short bf16_rne(float f) {
  unsigned u = __float_as_uint(f);
  unsigned r = u + 0x7FFFu + ((u >> 16) & 1u);
  return (unsigned short)(r >> 16);
}
__device__ __forceinline__ float bf16_to_f32(unsigned short h) {
  return __uint_as_float(((unsigned)h) << 16);
}

#if defined(__has_builtin)
#if __has_builtin(__builtin_amdgcn_cvt_pk_bf16_f32)
#define HAS_CVT_PK_BF16 1
#endif
#endif

__device__ __forceinline__ unsigned pack_bf2(float x, float y) {
#ifdef HAS_CVT_PK_BF16
  auto r = __builtin_amdgcn_cvt_pk_bf16_f32(x, y);
  unsigned u; __builtin_memcpy(&u, &r, 4);
  return u;
#else
  unsigned ux = __float_as_uint(x);
  unsigned uy = __float_as_uint(y);
  ux = ux + 0x7FFFu + ((ux >> 16) & 1u);
  uy = uy + 0x7FFFu + ((uy >> 16) & 1u);
  return (ux >> 16) | (uy & 0xFFFF0000u);
#endif
}
__device__ __forceinline__ v2f unpk_bf2(unsigned u) {
  v2f r; r.x = __uint_as_float(u << 16); r.y = __uint_as_float(u & 0xFFFF0000u);
  return r;
}
__device__ __forceinline__ v2f splat2(float x) { v2f r; r.x = x; r.y = x; return r; }
__device__ __forceinline__ v2f fma2(v2f a, v2f b, v2f c) { return __builtin_elementwise_fma(a, b, c); }
__device__ __forceinline__ v2f max2(v2f a, v2f b) { return __builtin_elementwise_max(a, b); }

// ---------------------------------------------------------------------------
// Prep, 1024 blocks x 512 threads.
__global__ __launch_bounds__(512) void prep_kernel(
    const float* __restrict__ h_obs, const float* __restrict__ fw1,
    const float* __restrict__ fb1, const float* __restrict__ fw2,
    const float* __restrict__ fb2, const float* __restrict__ pos_obs,
    const float* __restrict__ kw1, unsigned short* __restrict__ V_bf,
    unsigned short* __restrict__ AO_bf)
{
  if (blockIdx.x < 512) {
    __shared__ float s_red[2][2][256];
    __shared__ float s_hid[2][256];
    const int n  = threadIdx.x & 255;
    const int ks = threadIdx.x >> 8;      // 0..1
    const int r0 = blockIdx.x * 2;
    const int k0 = ks * 128;
    float a0 = 0.f, a1 = 0.f;
    #pragma unroll 8
    for (int kk = 0; kk < 128; ++kk) {
      int k = k0 + kk;
      float w = fw1[k * 256 + n];
      a0 = fmaf(h_obs[(r0 + 0) * 256 + k], w, a0);
      a1 = fmaf(h_obs[(r0 + 1) * 256 + k], w, a1);
    }
    s_red[ks][0][n] = a0; s_red[ks][1][n] = a1;
    __syncthreads();
    if (ks == 0) {
      float bb = fb1[n];
      s_hid[0][n] = fmaxf(s_red[0][0][n] + s_red[1][0][n] + bb, 0.f);
      s_hid[1][n] = fmaxf(s_red[0][1][n] + s_red[1][1][n] + bb, 0.f);
    }
    __syncthreads();
    float c0 = 0.f, c1 = 0.f;
    #pragma unroll 8
    for (int kk = 0; kk < 128; ++kk) {
      int k = k0 + kk;
      float w = fw2[k * 256 + n];
      c0 = fmaf(s_hid[0][k], w, c0);
      c1 = fmaf(s_hid[1][k], w, c1);
    }
    __syncthreads();
    s_red[ks][0][n] = c0; s_red[ks][1][n] = c1;
    __syncthreads();
    if (ks == 0) {
      float bb = fb2[n];
      V_bf[(size_t)(r0 + 0) * 256 + n] = bf16_rne(s_red[0][0][n] + s_red[1][0][n] + bb);
      V_bf[(size_t)(r0 + 1) * 256 + n] = bf16_rne(s_red[0][1][n] + s_red[1][1][n] + bb);
    }
  } else {
    const int i     = blockIdx.x - 512;   // 0..511
    const int b     = i >> 8;
    const int chunk = i & 255;
    const int ol    = threadIdx.x >> 8;
    const int j     = threadIdx.x & 255;
    const int o     = chunk * 2 + ol;
    float c0 = kw1[3 * 256 + j] - kw1[6 * 256 + j];
    float c1 = kw1[4 * 256 + j] - kw1[7 * 256 + j];
    float c2 = kw1[5 * 256 + j] - kw1[8 * 256 + j];
    const float* p = pos_obs + ((size_t)(b * NO + o)) * 3;
    AO_bf[(size_t)(b * NO + o) * 256 + j] =
        bf16_rne(fmaf(p[0], c0, fmaf(p[1], c1, p[2] * c2)));
  }
}

// ---------------------------------------------------------------------------
// Fused attention + out_proj. ONE query per block, 256 threads (4 waves).
// 1024 blocks -> 4 blocks/CU: 4 independent barrier domains per CU.
__global__ __launch_bounds__(256, 4) void attn_fused(
    const unsigned short* __restrict__ V_bf,   // (B*NO, 256) bf16
    const unsigned short* __restrict__ AO_bf,  // (B*NO, 256) bf16
    const float* __restrict__ kw1,       // (9, 256)
    const float* __restrict__ kb1,       // (256)
    const float* __restrict__ kw2,       // (256, 8)
    const float* __restrict__ kb2,       // (8)
    const float* __restrict__ log_sigma, // (8)
    const float* __restrict__ pos_obs,   // (B*NO, 3)
    const float* __restrict__ pos_query, // (B*NQ, 3)
    const float* __restrict__ ow, const float* __restrict__ obias,
    const float* __restrict__ vw, const float* __restrict__ vbias,
    float* __restrict__ out)
{
  __shared__ float s_logits[8 * LPAD];           // 16,512 B
  __shared__ __align__(16) char poolA[16384];    // Bfrags 16,384 | s_redC 8,320
  __shared__ __align__(16) char poolB[2048];     // aq 1K | s_hv 2K
  __shared__ float s_sum[8];
  __shared__ float s_invs2[8];
  __shared__ float s_kb2v[8];

  short8* Bhi    = (short8*)poolA;               // [kstep*64 + lane]
  short8* Blo    = (short8*)(poolA + 8192);
  float*  s_redC = (float*)poolA;                // [8][RPITCH] column-major
  float*  s_aq   = (float*)poolB;                // [j]
  float*  s_hv   = (float*)poolB;                // [mode*256 + hd]

  const int t  = threadIdx.x;
  const int bq = blockIdx.x;
  const int b  = bq >> 9;

  // ---- prologue -----------------------------------------------------------
  const float pqx = pos_query[bq * 3 + 0];
  const float pqy = pos_query[bq * 3 + 1];
  const float pqz = pos_query[bq * 3 + 2];
  // aq[j], j = t
  {
    const int j = t;
    float c0 = kw1[0 * 256 + j] + kw1[6 * 256 + j];
    float c1 = kw1[1 * 256 + j] + kw1[7 * 256 + j];
    float c2 = kw1[2 * 256 + j] + kw1[8 * 256 + j];
    s_aq[j] = fmaf(pqx, c0, fmaf(pqy, c1, fmaf(pqz, c2, kb1[j])));
  }
  // B fragments: kw2 split bf16 hi/lo; each thread covers 2 ksteps
  {
    const int lane = t & 63;
    const int nh = lane & 15;
    #pragma unroll
    for (int kk = 0; kk < 2; ++kk) {
      const int kstep = (t >> 6) + kk * 4;
      const int kb_ = kstep * 32 + ((lane >> 4) & 3) * 8;
      short8 hi8, lo8;
      #pragma unroll
      for (int i = 0; i < 8; ++i) {
        float v = (nh < 8) ? kw2[(kb_ + i) * 8 + nh] : 0.f;
        unsigned short h = bf16_rne(v);
        hi8[i] = (short)h;
        lo8[i] = (short)bf16_rne(v - bf16_to_f32(h));
      }
      Bhi[kstep * 64 + lane] = hi8;
      Blo[kstep * 64 + lane] = lo8;
    }
  }
  if (t < 8) {
    float s = expf(log_sigma[t]);
    s_invs2[t] = 1.0f / (s * s + 1e-6f);
    s_kb2v[t]  = kb2[t];
  }
  __syncthreads();

  // ---- rbf prefill, o = t and t+256 ---------------------------------------
  #pragma unroll
  for (int oo = 0; oo < 2; ++oo) {
    const int o = t + oo * 256;
    const float* p = pos_obs + (size_t)(b * NO + o) * 3;
    float r0 = pqx - p[0], r1 = pqy - p[1], r2 = pqz - p[2];
    float d2 = r0 * r0 + r1 * r1 + r2 * r2;
    #pragma unroll
    for (int h = 0; h < 8; ++h)
      s_logits[h * LPAD + o] = logf(expf(-d2 * s_invs2[h]) + 1e-8f) + s_kb2v[h];
  }

  // ---- phase 1: MFMA delta ------------------------------------------------
  {
    const int wave = t >> 6, lane = t & 63;
    const int quad = lane >> 4, mrow = lane & 15;
    const int tb   = wave * 8;                   // 8 o-tiles per wave
    f32x4 C[8];
    #pragma unroll
    for (int jt = 0; jt < 8; ++jt) C[jt] = (f32x4){0.f, 0.f, 0.f, 0.f};

    for (int kstep = 0; kstep < 8; ++kstep) {
      const int koff = kstep * 32 + quad * 8;
      const v2f* aqp = (const v2f*)(s_aq + koff);
      v2f aq[4];
      #pragma unroll
      for (int i = 0; i < 4; ++i) aq[i] = aqp[i];
      short8 bhi = Bhi[kstep * 64 + lane];
      short8 blo = Blo[kstep * 64 + lane];
      #pragma unroll 4
      for (int jt = 0; jt < 8; ++jt) {
        const int o = (tb + jt) * 16 + mrow;
        int4 u = *(const int4*)(AO_bf + ((size_t)(b * NO + o) << 8) + koff);
        v2f z = splat2(0.f);
        v2f h0 = max2(aq[0] + unpk_bf2((unsigned)u.x), z);
        v2f h1 = max2(aq[1] + unpk_bf2((unsigned)u.y), z);
        v2f h2 = max2(aq[2] + unpk_bf2((unsigned)u.z), z);
        v2f h3 = max2(aq[3] + unpk_bf2((unsigned)u.w), z);
        int4 af;
        af.x = (int)pack_bf2(h0.x, h0.y); af.y = (int)pack_bf2(h1.x, h1.y);
        af.z = (int)pack_bf2(h2.x, h2.y); af.w = (int)pack_bf2(h3.x, h3.y);
        short8 a = __builtin_bit_cast(short8, af);
        C[jt] = __builtin_amdgcn_mfma_f32_16x16x32_bf16(a, bhi, C[jt], 0, 0, 0);
        C[jt] = __builtin_amdgcn_mfma_f32_16x16x32_bf16(a, blo, C[jt], 0, 0, 0);
      }
    }
    __syncthreads();   // rbf prefill complete before += epilogue

    const int h = lane & 15;
    if (h < 8) {
      #pragma unroll
      for (int jt = 0; jt < 8; ++jt) {
        const int ob = (tb + jt) * 16 + quad * 4;
        #pragma unroll
        for (int r = 0; r < 4; ++r)
          s_logits[h * LPAD + ob + r] += C[jt][r];
      }
    }
  }
  __syncthreads();

  // ---- phase 2: softmax (4 waves x 2 h-rows) ------------------------------
  {
    const int wave = t >> 6, lane = t & 63;
    #pragma unroll
    for (int cc = 0; cc < 2; ++cc) {
      const int h = wave * 2 + cc;
      float* pl = &s_logits[h * LPAD];
      float l[8];
      float m = -1e30f;
      #pragma unroll
      for (int k = 0; k < 8; ++k) {
        l[k] = pl[k * 64 + lane];
        m = fmaxf(m, l[k]);
      }
      #pragma unroll
      for (int off = 32; off >= 1; off >>= 1) m = fmaxf(m, __shfl_xor(m, off, 64));
      float s = 0.f;
      #pragma unroll
      for (int k = 0; k < 8; ++k) {
        float p = expf(l[k] - m);
        pl[k * 64 + lane] = p;
        s += p;
      }
      #pragma unroll
      for (int off = 32; off >= 1; off >>= 1) s += __shfl_xor(s, off, 64);
      if (lane == 0) s_sum[h] = s;
    }
  }
  __syncthreads();

  // ---- phase 3: PV + P V^2 ------------------------------------------------
  {
    const int s  = t >> 6;                 // o-slice of 128
    const int r  = t & 63;
    const int h  = r >> 3, dg = r & 7;
    const unsigned short* vb_ = V_bf + ((size_t)(b * NO) << 8) + h * 32 + dg * 4;
    const float* P = &s_logits[h * LPAD + s * 128];
    v2f s1a = splat2(0.f), s1b = splat2(0.f), s2a = splat2(0.f), s2b = splat2(0.f);
    const int o0 = s * 128;
    #pragma unroll 2
    for (int oi = 0; oi < 128; oi += 4) {
      float4 pv = *(const float4*)&P[oi];       // ds_read_b128 broadcast
      #pragma unroll
      for (int i = 0; i < 4; ++i) {
        const int o = o0 + oi + i;
        uint2 vv = *(const uint2*)(vb_ + ((size_t)o << 8));
        v2f va  = unpk_bf2(vv.x);
        v2f vb2 = unpk_bf2(vv.y);
        v2f p = splat2((&pv.x)[i]);
        s1a = fma2(p, va, s1a);  s1b = fma2(p, vb2, s1b);
        v2f ta = p * va, tb = p * vb2;
        s2a = fma2(ta, va, s2a); s2b = fma2(tb, vb2, s2b);
      }
    }
    __syncthreads();   // everyone done reading s_logits region? (redC overlays Bfrags, safe) 
    s_redC[0 * RPITCH + t] = s1a.x; s_redC[1 * RPITCH + t] = s1a.y;
    s_redC[2 * RPITCH + t] = s1b.x; s_redC[3 * RPITCH + t] = s1b.y;
    s_redC[4 * RPITCH + t] = s2a.x; s_redC[5 * RPITCH + t] = s2a.y;
    s_redC[6 * RPITCH + t] = s2b.x; s_redC[7 * RPITCH + t] = s2b.y;
  }
  __syncthreads();

  // ---- reduce 4 o-slices -> s_hv ------------------------------------------
  {
    const int hd = t, h = hd >> 5, d = hd & 31, dg = d >> 2, c = d & 3;
    float S1 = 0.f, S2 = 0.f;
    #pragma unroll
    for (int s = 0; s < 4; ++s) {
      const int idx = s * 64 + h * 8 + dg;
      S1 += s_redC[c * RPITCH + idx];
      S2 += s_redC[(4 + c) * RPITCH + idx];
    }
    float inv = 1.0f / s_sum[h];
    float m1 = S1 * inv;
    float va = fmaxf(S2 * inv - m1 * m1, 0.f);
    __syncthreads();   // s_aq dead; s_hv overlays poolB
    s_hv[0 * 256 + hd] = m1;
    s_hv[1 * 256 + hd] = va;
  }
  __syncthreads();

  // ---- phase 4: out_proj, 1 thread per (mode, n) --------------------------
  {
    const int mode = t >> 7, n = t & 127;
    const float* W  = mode ? vw : ow;
    const float* X  = s_hv + mode * 256;
    float acc = mode ? vbias[n] : obias[n];
    #pragma unroll 4
    for (int k = 0; k < 256; k += 4) {
      float4 x = *(const float4*)&X[k];
      acc = fmaf(x.x, W[(k + 0) * 128 + n], acc);
      acc = fmaf(x.y, W[(k + 1) * 128 + n], acc);
      acc = fmaf(x.z, W[(k + 2) * 128 + n], acc);
      acc = fmaf(x.w, W[(k + 3) * 128 + n], acc);
    }
    if (mode) acc = softplus_f(acc);
    out[(size_t)mode * (NB * NQ * OUT_DIM) + (size_t)bq * OUT_DIM + n] = acc;
  }
}

// ---------------------------------------------------------------------------
extern "C" void kernel_launch(void* const* d_in, const int* in_sizes, int n_in,
                              void* d_out, int out_size, void* d_ws, size_t ws_size,
                              hipStream_t stream)
{
  const float* h_obs     = (const float*)d_in[0];
  const float* pos_obs   = (const float*)d_in[1];
  const float* pos_query = (const float*)d_in[2];
  const float* fw1       = (const float*)d_in[3];
  const float* fb1       = (const float*)d_in[4];
  const float* fw2       = (const float*)d_in[5];
  const float* fb2       = (const float*)d_in[6];
  const float* log_sigma = (const float*)d_in[7];
  const float* kw1       = (const float*)d_in[8];
  const float* kb1       = (const float*)d_in[9];
  const float* kw2       = (const float*)d_in[10];
  const float* kb2       = (const float*)d_in[11];
  const float* ow        = (const float*)d_in[12];
  const float* ob        = (const float*)d_in[13];
  const float* vw        = (const float*)d_in[14];
  const float* vb        = (const float*)d_in[15];

  float* out = (float*)d_out;
  unsigned short* ws = (unsigned short*)d_ws;

  unsigned short* V_bf  = ws;            // 262144 ushort = 512 KB
  unsigned short* AO_bf = ws + 262144;

  prep_kernel<<<1024, 512, 0, stream>>>(h_obs, fw1, fb1, fw2, fb2,
                                        pos_obs, kw1, V_bf, AO_bf);
  attn_fused<<<NB * NQ, 256, 0, stream>>>(V_bf, AO_bf, kw1, kb1, kw2, kb2,
                                          log_sigma, pos_obs, pos_query,
                                          ow, ob, vw, vb, out);
}

// Round 10
// 159.754 us; speedup vs baseline: 1.0306x; 1.0306x over previous
//
#include <hip/hip_runtime.h>
#include <math.h>

#define NB 2
#define NO 512
#define NQ 512
#define OUT_DIM 128
#define LPAD 516   // logits row pitch (floats); 516%32=4 -> conflict-spread
#define RP2  516   // reduce pitch (cols = 512 threads)

typedef __attribute__((ext_vector_type(8))) short short8;   // 8 bf16
typedef __attribute__((ext_vector_type(4))) float f32x4;    // MFMA acc
typedef float v2f __attribute__((ext_vector_type(2)));

__device__ __forceinline__ float softplus_f(float x) {
  return x > 0.0f ? x + __logf(1.0f + __expf(-x)) : __logf(1.0f + __expf(x));
}
__device__ __forceinline__ unsigned short bf16_rne(float f) {
  unsigned u = __float_as_uint(f);
  unsigned r = u + 0x7FFFu + ((u >> 16) & 1u);
  return (unsigned short)(r >> 16);
}
__device__ __forceinline__ float bf16_to_f32(unsigned short h) {
  return __uint_as_float(((unsigned)h) << 16);
}

#if defined(__has_builtin)
#if __has_builtin(__builtin_amdgcn_cvt_pk_bf16_f32)
#define HAS_CVT_PK_BF16 1
#endif
#endif

__device__ __forceinline__ unsigned pack_bf2(float x, float y) {
#ifdef HAS_CVT_PK_BF16
  auto r = __builtin_amdgcn_cvt_pk_bf16_f32(x, y);
  unsigned u; __builtin_memcpy(&u, &r, 4);
  return u;
#else
  unsigned ux = __float_as_uint(x);
  unsigned uy = __float_as_uint(y);
  ux = ux + 0x7FFFu + ((ux >> 16) & 1u);
  uy = uy + 0x7FFFu + ((uy >> 16) & 1u);
  return (ux >> 16) | (uy & 0xFFFF0000u);
#endif
}
__device__ __forceinline__ v2f unpk_bf2(unsigned u) {
  v2f r; r.x = __uint_as_float(u << 16); r.y = __uint_as_float(u & 0xFFFF0000u);
  return r;
}
__device__ __forceinline__ v2f splat2(float x) { v2f r; r.x = x; r.y = x; return r; }
__device__ __forceinline__ v2f fma2(v2f a, v2f b, v2f c) { return __builtin_elementwise_fma(a, b, c); }
__device__ __forceinline__ v2f max2(v2f a, v2f b) { return __builtin_elementwise_max(a, b); }

// ---------------------------------------------------------------------------
// Prep, 1024 blocks x 512 threads (unchanged from R9 - works).
__global__ __launch_bounds__(512) void prep_kernel(
    const float* __restrict__ h_obs, const float* __restrict__ fw1,
    const float* __restrict__ fb1, const float* __restrict__ fw2,
    const float* __restrict__ fb2, const float* __restrict__ pos_obs,
    const float* __restrict__ kw1, unsigned short* __restrict__ V_bf,
    unsigned short* __restrict__ AO_bf)
{
  if (blockIdx.x < 512) {
    __shared__ float s_red[2][2][256];
    __shared__ float s_hid[2][256];
    const int n  = threadIdx.x & 255;
    const int ks = threadIdx.x >> 8;      // 0..1
    const int r0 = blockIdx.x * 2;
    const int k0 = ks * 128;
    float a0 = 0.f, a1 = 0.f;
    #pragma unroll 8
    for (int kk = 0; kk < 128; ++kk) {
      int k = k0 + kk;
      float w = fw1[k * 256 + n];
      a0 = fmaf(h_obs[(r0 + 0) * 256 + k], w, a0);
      a1 = fmaf(h_obs[(r0 + 1) * 256 + k], w, a1);
    }
    s_red[ks][0][n] = a0; s_red[ks][1][n] = a1;
    __syncthreads();
    if (ks == 0) {
      float bb = fb1[n];
      s_hid[0][n] = fmaxf(s_red[0][0][n] + s_red[1][0][n] + bb, 0.f);
      s_hid[1][n] = fmaxf(s_red[0][1][n] + s_red[1][1][n] + bb, 0.f);
    }
    __syncthreads();
    float c0 = 0.f, c1 = 0.f;
    #pragma unroll 8
    for (int kk = 0; kk < 128; ++kk) {
      int k = k0 + kk;
      float w = fw2[k * 256 + n];
      c0 = fmaf(s_hid[0][k], w, c0);
      c1 = fmaf(s_hid[1][k], w, c1);
    }
    __syncthreads();
    s_red[ks][0][n] = c0; s_red[ks][1][n] = c1;
    __syncthreads();
    if (ks == 0) {
      float bb = fb2[n];
      V_bf[(size_t)(r0 + 0) * 256 + n] = bf16_rne(s_red[0][0][n] + s_red[1][0][n] + bb);
      V_bf[(size_t)(r0 + 1) * 256 + n] = bf16_rne(s_red[0][1][n] + s_red[1][1][n] + bb);
    }
  } else {
    const int i     = blockIdx.x - 512;   // 0..511
    const int b     = i >> 8;
    const int chunk = i & 255;
    const int ol    = threadIdx.x >> 8;
    const int j     = threadIdx.x & 255;
    const int o     = chunk * 2 + ol;
    float c0 = kw1[3 * 256 + j] - kw1[6 * 256 + j];
    float c1 = kw1[4 * 256 + j] - kw1[7 * 256 + j];
    float c2 = kw1[5 * 256 + j] - kw1[8 * 256 + j];
    const float* p = pos_obs + ((size_t)(b * NO + o)) * 3;
    AO_bf[(size_t)(b * NO + o) * 256 + j] =
        bf16_rne(fmaf(p[0], c0, fmaf(p[1], c1, p[2] * c2)));
  }
}

// ---------------------------------------------------------------------------
// Fused attention + out_proj. QT=2, 512 threads (8 waves), 6 barriers.
__global__ __launch_bounds__(512) void attn_fused(
    const unsigned short* __restrict__ V_bf,   // (B*NO, 256) bf16
    const unsigned short* __restrict__ AO_bf,  // (B*NO, 256) bf16
    const float* __restrict__ kw1,       // (9, 256)
    const float* __restrict__ kb1,       // (256)
    const float* __restrict__ kw2,       // (256, 8)
    const float* __restrict__ kb2,       // (8)
    const float* __restrict__ log_sigma, // (8)
    const float* __restrict__ pos_obs,   // (B*NO, 3)
    const float* __restrict__ pos_query, // (B*NQ, 3)
    const float* __restrict__ ow, const float* __restrict__ obias,
    const float* __restrict__ vw, const float* __restrict__ vbias,
    float* __restrict__ out)
{
  __shared__ float s_logits[2][8 * LPAD];        // 33,024 B
  __shared__ __align__(16) char poolA[33024];    // Bfrags 16,384 | redC 16x516x4 | s_pred 4,096
  __shared__ __align__(16) char poolB[6144];     // aq 2K + d2 4K | s_hv 4K
  __shared__ float s_sum[2][8];
  __shared__ float s_invs2[8];
  __shared__ float s_kb2v[8];

  short8* Bhi    = (short8*)poolA;               // [kstep*64 + lane]
  short8* Blo    = (short8*)(poolA + 8192);
  float*  s_redC = (float*)poolA;                // [16][RP2]
  float*  s_pred = (float*)poolA;                // [ks][mode][q][128]
  float*  s_aq   = (float*)poolB;                // [q*256 + j]
  float*  s_d2   = (float*)(poolB + 2048);       // [q*512 + o]
  float*  s_hv   = (float*)poolB;                // [(q*2+mode)*256 + hd]

  const int t   = threadIdx.x;
  const int bq0 = blockIdx.x * 2;
  const int b   = bq0 >> 9;

  // ---- prologue -----------------------------------------------------------
  float pqx[2], pqy[2], pqz[2];
  #pragma unroll
  for (int q = 0; q < 2; ++q) {
    pqx[q] = pos_query[(bq0 + q) * 3 + 0];
    pqy[q] = pos_query[(bq0 + q) * 3 + 1];
    pqz[q] = pos_query[(bq0 + q) * 3 + 2];
  }
  // aq[q][j]
  {
    const int q = t >> 8, j = t & 255;
    float c0 = kw1[0 * 256 + j] + kw1[6 * 256 + j];
    float c1 = kw1[1 * 256 + j] + kw1[7 * 256 + j];
    float c2 = kw1[2 * 256 + j] + kw1[8 * 256 + j];
    s_aq[q * 256 + j] =
        fmaf(pqx[q], c0, fmaf(pqy[q], c1, fmaf(pqz[q], c2, kb1[j])));
  }
  // d2[q][o], o = t
  {
    const int o = t;
    const float* p = pos_obs + (size_t)(b * NO + o) * 3;
    float px = p[0], py = p[1], pz = p[2];
    #pragma unroll
    for (int q = 0; q < 2; ++q) {
      float r0 = pqx[q] - px, r1 = pqy[q] - py, r2 = pqz[q] - pz;
      s_d2[q * 512 + o] = r0 * r0 + r1 * r1 + r2 * r2;
    }
  }
  // B fragments: kw2 split bf16 hi/lo
  {
    const int kstep = t >> 6, lane = t & 63;
    const int nh = lane & 15;
    const int kb_ = kstep * 32 + ((lane >> 4) & 3) * 8;
    short8 hi8, lo8;
    #pragma unroll
    for (int i = 0; i < 8; ++i) {
      float v = (nh < 8) ? kw2[(kb_ + i) * 8 + nh] : 0.f;
      unsigned short h = bf16_rne(v);
      hi8[i] = (short)h;
      lo8[i] = (short)bf16_rne(v - bf16_to_f32(h));
    }
    Bhi[kstep * 64 + lane] = hi8;
    Blo[kstep * 64 + lane] = lo8;
  }
  if (t < 8) {
    float s = __expf(log_sigma[t]);
    s_invs2[t] = 1.0f / (s * s + 1e-6f);
    s_kb2v[t]  = kb2[t];
  }
  __syncthreads();                                           // B1

  // ---- phase 1: MFMA delta; epilogue computes full logits -----------------
  {
    const int wave = t >> 6, lane = t & 63;
    const int quad = lane >> 4, mrow = lane & 15;
    const int tb   = wave * 4;                   // 4 o-tiles per wave, both q
    f32x4 C[2][4];
    #pragma unroll
    for (int q = 0; q < 2; ++q)
      #pragma unroll
      for (int jt = 0; jt < 4; ++jt) C[q][jt] = (f32x4){0.f, 0.f, 0.f, 0.f};

    for (int kstep = 0; kstep < 8; ++kstep) {
      const int koff = kstep * 32 + quad * 8;
      const v2f* aqp0 = (const v2f*)(s_aq + koff);
      const v2f* aqp1 = (const v2f*)(s_aq + 256 + koff);
      v2f aq0[4], aq1[4];
      #pragma unroll
      for (int i = 0; i < 4; ++i) { aq0[i] = aqp0[i]; aq1[i] = aqp1[i]; }
      short8 bhi = Bhi[kstep * 64 + lane];
      short8 blo = Blo[kstep * 64 + lane];
      #pragma unroll
      for (int jt = 0; jt < 4; ++jt) {
        const int o = (tb + jt) * 16 + mrow;
        int4 u = *(const int4*)(AO_bf + ((size_t)(b * NO + o) << 8) + koff);
        v2f ao[4];
        ao[0] = unpk_bf2((unsigned)u.x); ao[1] = unpk_bf2((unsigned)u.y);
        ao[2] = unpk_bf2((unsigned)u.z); ao[3] = unpk_bf2((unsigned)u.w);
        v2f z = splat2(0.f);
        int4 af0, af1;
        {
          v2f h0 = max2(aq0[0] + ao[0], z), h1 = max2(aq0[1] + ao[1], z);
          v2f h2 = max2(aq0[2] + ao[2], z), h3 = max2(aq0[3] + ao[3], z);
          af0.x = (int)pack_bf2(h0.x, h0.y); af0.y = (int)pack_bf2(h1.x, h1.y);
          af0.z = (int)pack_bf2(h2.x, h2.y); af0.w = (int)pack_bf2(h3.x, h3.y);
        }
        {
          v2f h0 = max2(aq1[0] + ao[0], z), h1 = max2(aq1[1] + ao[1], z);
          v2f h2 = max2(aq1[2] + ao[2], z), h3 = max2(aq1[3] + ao[3], z);
          af1.x = (int)pack_bf2(h0.x, h0.y); af1.y = (int)pack_bf2(h1.x, h1.y);
          af1.z = (int)pack_bf2(h2.x, h2.y); af1.w = (int)pack_bf2(h3.x, h3.y);
        }
        short8 a0 = __builtin_bit_cast(short8, af0);
        short8 a1 = __builtin_bit_cast(short8, af1);
        C[0][jt] = __builtin_amdgcn_mfma_f32_16x16x32_bf16(a0, bhi, C[0][jt], 0, 0, 0);
        C[0][jt] = __builtin_amdgcn_mfma_f32_16x16x32_bf16(a0, blo, C[0][jt], 0, 0, 0);
        C[1][jt] = __builtin_amdgcn_mfma_f32_16x16x32_bf16(a1, bhi, C[1][jt], 0, 0, 0);
        C[1][jt] = __builtin_amdgcn_mfma_f32_16x16x32_bf16(a1, blo, C[1][jt], 0, 0, 0);
      }
    }
    // epilogue: lane holds D[n=h][m=quad*4+r]; full logit = rbf + delta
    const int h = lane & 15;
    if (h < 8) {
      const float inv = s_invs2[h];
      const float kbv = s_kb2v[h];
      #pragma unroll
      for (int q = 0; q < 2; ++q)
        #pragma unroll
        for (int jt = 0; jt < 4; ++jt) {
          const int ob = (tb + jt) * 16 + quad * 4;
          #pragma unroll
          for (int r = 0; r < 4; ++r) {
            const int o = ob + r;
            float d2 = s_d2[q * 512 + o];
            float lg = __logf(__expf(-d2 * inv) + 1e-8f) + kbv + C[q][jt][r];
            s_logits[q][h * LPAD + o] = lg;
          }
        }
    }
  }
  __syncthreads();                                           // B2

  // ---- phase 2: softmax (8 waves x 2 (q,h) rows), native exp --------------
  {
    const int wave = t >> 6, lane = t & 63;
    #pragma unroll
    for (int cc = 0; cc < 2; ++cc) {
      const int c = wave * 2 + cc;
      const int q = c >> 3, h = c & 7;
      float* pl = &s_logits[q][h * LPAD];
      float l[8];
      float m = -1e30f;
      #pragma unroll
      for (int k = 0; k < 8; ++k) {
        l[k] = pl[k * 64 + lane];
        m = fmaxf(m, l[k]);
      }
      #pragma unroll
      for (int off = 32; off >= 1; off >>= 1) m = fmaxf(m, __shfl_xor(m, off, 64));
      float s = 0.f;
      #pragma unroll
      for (int k = 0; k < 8; ++k) {
        float p = __expf(l[k] - m);
        pl[k * 64 + lane] = p;
        s += p;
      }
      #pragma unroll
      for (int off = 32; off >= 1; off >>= 1) s += __shfl_xor(s, off, 64);
      if (lane == 0) s_sum[q][h] = s;
    }
  }
  __syncthreads();                                           // B3

  // ---- phase 3: PV + P V^2, 8 d per thread, uint4 V loads -----------------
  {
    const int q  = t >> 8;
    const int rr = t & 255;
    const int s  = rr >> 5;              // o-slice of 64
    const int h  = (rr >> 2) & 7;
    const int dg = rr & 3;               // d-octet
    const unsigned short* vb_ = V_bf + ((size_t)(b * NO) << 8) + h * 32 + dg * 8;
    const float* P = &s_logits[q][h * LPAD + s * 64];
    v2f s1[4], s2[4];
    #pragma unroll
    for (int i = 0; i < 4; ++i) { s1[i] = splat2(0.f); s2[i] = splat2(0.f); }
    const int o0 = s * 64;
    #pragma unroll 2
    for (int oi = 0; oi < 64; oi += 4) {
      float4 pv = *(const float4*)&P[oi];       // ds_read_b128 broadcast
      #pragma unroll
      for (int i = 0; i < 4; ++i) {
        const int o = o0 + oi + i;
        uint4 vv = *(const uint4*)(vb_ + ((size_t)o << 8));
        v2f p = splat2((&pv.x)[i]);
        v2f v0 = unpk_bf2(vv.x), v1 = unpk_bf2(vv.y);
        v2f v2 = unpk_bf2(vv.z), v3 = unpk_bf2(vv.w);
        s1[0] = fma2(p, v0, s1[0]); s1[1] = fma2(p, v1, s1[1]);
        s1[2] = fma2(p, v2, s1[2]); s1[3] = fma2(p, v3, s1[3]);
        v2f t0 = p * v0, t1 = p * v1, t2 = p * v2, t3 = p * v3;
        s2[0] = fma2(t0, v0, s2[0]); s2[1] = fma2(t1, v1, s2[1]);
        s2[2] = fma2(t2, v2, s2[2]); s2[3] = fma2(t3, v3, s2[3]);
      }
    }
    // redC rows: e = d&7 -> row e (PV) / 8+e (PV^2); col = t
    #pragma unroll
    for (int i = 0; i < 4; ++i) {
      s_redC[(2 * i + 0) * RP2 + t] = s1[i].x;
      s_redC[(2 * i + 1) * RP2 + t] = s1[i].y;
      s_redC[(8 + 2 * i + 0) * RP2 + t] = s2[i].x;
      s_redC[(8 + 2 * i + 1) * RP2 + t] = s2[i].y;
    }
  }
  __syncthreads();                                           // B4

  // ---- reduce 8 o-slices, both q in one pass -> s_hv ----------------------
  {
    const int q  = t >> 8;
    const int hd = t & 255;
    const int h  = hd >> 5, d = hd & 31;
    const int dgr = d >> 3, c = d & 7;
    float S1 = 0.f, S2 = 0.f;
    #pragma unroll
    for (int s = 0; s < 8; ++s) {
      const int col = q * 256 + s * 32 + h * 4 + dgr;
      S1 += s_redC[c * RP2 + col];
      S2 += s_redC[(8 + c) * RP2 + col];
    }
    float inv = 1.0f / s_sum[q][h];
    float m1 = S1 * inv;
    float va = fmaxf(S2 * inv - m1 * m1, 0.f);
    __syncthreads();                                         // B5 (aq/d2 dead)
    s_hv[(q * 2 + 0) * 256 + hd] = m1;
    s_hv[(q * 2 + 1) * 256 + hd] = va;
  }
  __syncthreads();                                           // B6

  // ---- phase 4: out_proj, k-split 2 ---------------------------------------
  {
    const int ks = t >> 8, mode = (t >> 7) & 1, n = t & 127;
    const float* W  = mode ? vw : ow;
    const float* X0 = s_hv + mode * 256;        // q0
    const float* X1 = s_hv + (2 + mode) * 256;  // q1
    float a0 = 0.f, a1 = 0.f;
    const int k0 = ks * 128;
    #pragma unroll 4
    for (int k = k0; k < k0 + 128; k += 4) {
      float4 x0 = *(const float4*)&X0[k];
      float4 x1 = *(const float4*)&X1[k];
      float w0 = W[(k + 0) * 128 + n];
      float w1 = W[(k + 1) * 128 + n];
      float w2 = W[(k + 2) * 128 + n];
      float w3 = W[(k + 3) * 128 + n];
      a0 = fmaf(x0.x, w0, a0); a1 = fmaf(x1.x, w0, a1);
      a0 = fmaf(x0.y, w1, a0); a1 = fmaf(x1.y, w1, a1);
      a0 = fmaf(x0.z, w2, a0); a1 = fmaf(x1.z, w2, a1);
      a0 = fmaf(x0.w, w3, a0); a1 = fmaf(x1.w, w3, a1);
    }
    __syncthreads();                            // redC dead; reuse as s_pred
    s_pred[((ks * 2 + mode) * 2 + 0) * 128 + n] = a0;
    s_pred[((ks * 2 + mode) * 2 + 1) * 128 + n] = a1;
  }
  __syncthreads();
  {
    const int q = t >> 8, mode = (t >> 7) & 1, n = t & 127;
    float v = s_pred[((0 * 2 + mode) * 2 + q) * 128 + n]
            + s_pred[((1 * 2 + mode) * 2 + q) * 128 + n]
            + (mode ? vbias[n] : obias[n]);
    if (mode) v = softplus_f(v);
    out[(size_t)mode * (NB * NQ * OUT_DIM) + (size_t)(bq0 + q) * OUT_DIM + n] = v;
  }
}

// ---------------------------------------------------------------------------
extern "C" void kernel_launch(void* const* d_in, const int* in_sizes, int n_in,
                              void* d_out, int out_size, void* d_ws, size_t ws_size,
                              hipStream_t stream)
{
  const float* h_obs     = (const float*)d_in[0];
  const float* pos_obs   = (const float*)d_in[1];
  const float* pos_query = (const float*)d_in[2];
  const float* fw1       = (const float*)d_in[3];
  const float* fb1       = (const float*)d_in[4];
  const float* fw2       = (const float*)d_in[5];
  const float* fb2       = (const float*)d_in[6];
  const float* log_sigma = (const float*)d_in[7];
  const float* kw1       = (const float*)d_in[8];
  const float* kb1       = (const float*)d_in[9];
  const float* kw2       = (const float*)d_in[10];
  const float* kb2       = (const float*)d_in[11];
  const float* ow        = (const float*)d_in[12];
  const float* ob        = (const float*)d_in[13];
  const float* vw        = (const float*)d_in[14];
  const float* vb        = (const float*)d_in[15];

  float* out = (float*)d_out;
  unsigned short* ws = (unsigned short*)d_ws;

  unsigned short* V_bf  = ws;            // 262144 ushort = 512 KB
  unsigned short* AO_bf = ws + 262144;

  prep_kernel<<<1024, 512, 0, stream>>>(h_obs, fw1, fb1, fw2, fb2,
                                        pos_obs, kw1, V_bf, AO_bf);
  attn_fused<<<NB * NQ / 2, 512, 0, stream>>>(V_bf, AO_bf, kw1, kb1, kw2, kb2,
                                              log_sigma, pos_obs, pos_query,
                                              ow, ob, vw, vb, out);
}

// Round 11
// 154.714 us; speedup vs baseline: 1.0641x; 1.0326x over previous
//
#include <hip/hip_runtime.h>
#include <math.h>

#define NB 2
#define NO 512
#define NQ 512
#define OUT_DIM 128
#define LPAD 516   // logits row pitch (floats); 516%32=4 -> conflict-spread
#define RP2  516   // reduce pitch (cols = 512 threads)

typedef __attribute__((ext_vector_type(8))) short short8;   // 8 bf16
typedef __attribute__((ext_vector_type(4))) float f32x4;    // MFMA acc
typedef float v2f __attribute__((ext_vector_type(2)));

__device__ __forceinline__ float softplus_f(float x) {
  return x > 0.0f ? x + __logf(1.0f + __expf(-x)) : __logf(1.0f + __expf(x));
}
__device__ __forceinline__ unsigned short bf16_rne(float f) {
  unsigned u = __float_as_uint(f);
  unsigned r = u + 0x7FFFu + ((u >> 16) & 1u);
  return (unsigned short)(r >> 16);
}
__device__ __forceinline__ float bf16_to_f32(unsigned short h) {
  return __uint_as_float(((unsigned)h) << 16);
}

#if defined(__has_builtin)
#if __has_builtin(__builtin_amdgcn_cvt_pk_bf16_f32)
#define HAS_CVT_PK_BF16 1
#endif
#endif

__device__ __forceinline__ unsigned pack_bf2(float x, float y) {
#ifdef HAS_CVT_PK_BF16
  auto r = __builtin_amdgcn_cvt_pk_bf16_f32(x, y);
  unsigned u; __builtin_memcpy(&u, &r, 4);
  return u;
#else
  unsigned ux = __float_as_uint(x);
  unsigned uy = __float_as_uint(y);
  ux = ux + 0x7FFFu + ((ux >> 16) & 1u);
  uy = uy + 0x7FFFu + ((uy >> 16) & 1u);
  return (ux >> 16) | (uy & 0xFFFF0000u);
#endif
}
__device__ __forceinline__ v2f unpk_bf2(unsigned u) {
  v2f r; r.x = __uint_as_float(u << 16); r.y = __uint_as_float(u & 0xFFFF0000u);
  return r;
}
__device__ __forceinline__ v2f splat2(float x) { v2f r; r.x = x; r.y = x; return r; }
__device__ __forceinline__ v2f fma2(v2f a, v2f b, v2f c) { return __builtin_elementwise_fma(a, b, c); }
__device__ __forceinline__ v2f max2(v2f a, v2f b) { return __builtin_elementwise_max(a, b); }

// ---------------------------------------------------------------------------
// Prep (R7 config): 512 blocks x 1024 threads.
// Blocks 0..255: fused 2-layer MLP (4 rows, k-split 4) -> V bf16.
// Blocks 256..511: AO bf16, 4 o-rows/block.
__global__ __launch_bounds__(1024) void prep_kernel(
    const float* __restrict__ h_obs, const float* __restrict__ fw1,
    const float* __restrict__ fb1, const float* __restrict__ fw2,
    const float* __restrict__ fb2, const float* __restrict__ pos_obs,
    const float* __restrict__ kw1, unsigned short* __restrict__ V_bf,
    unsigned short* __restrict__ AO_bf)
{
  if (blockIdx.x < 256) {
    __shared__ float s_red[4][4][256];
    __shared__ float s_hid[4][256];
    const int n  = threadIdx.x & 255;
    const int ks = threadIdx.x >> 8;
    const int r0 = blockIdx.x * 4;
    const int k0 = ks * 64;
    float a0 = 0.f, a1 = 0.f, a2 = 0.f, a3 = 0.f;
    #pragma unroll 8
    for (int kk = 0; kk < 64; ++kk) {
      int k = k0 + kk;
      float w = fw1[k * 256 + n];
      a0 = fmaf(h_obs[(r0 + 0) * 256 + k], w, a0);
      a1 = fmaf(h_obs[(r0 + 1) * 256 + k], w, a1);
      a2 = fmaf(h_obs[(r0 + 2) * 256 + k], w, a2);
      a3 = fmaf(h_obs[(r0 + 3) * 256 + k], w, a3);
    }
    s_red[ks][0][n] = a0; s_red[ks][1][n] = a1;
    s_red[ks][2][n] = a2; s_red[ks][3][n] = a3;
    __syncthreads();
    if (ks == 0) {
      float bb = fb1[n];
      #pragma unroll
      for (int r = 0; r < 4; ++r) {
        float v = s_red[0][r][n] + s_red[1][r][n] + s_red[2][r][n] + s_red[3][r][n] + bb;
        s_hid[r][n] = fmaxf(v, 0.f);
      }
    }
    __syncthreads();
    float c0 = 0.f, c1 = 0.f, c2 = 0.f, c3 = 0.f;
    #pragma unroll 8
    for (int kk = 0; kk < 64; ++kk) {
      int k = k0 + kk;
      float w = fw2[k * 256 + n];
      c0 = fmaf(s_hid[0][k], w, c0);
      c1 = fmaf(s_hid[1][k], w, c1);
      c2 = fmaf(s_hid[2][k], w, c2);
      c3 = fmaf(s_hid[3][k], w, c3);
    }
    __syncthreads();
    s_red[ks][0][n] = c0; s_red[ks][1][n] = c1;
    s_red[ks][2][n] = c2; s_red[ks][3][n] = c3;
    __syncthreads();
    if (ks == 0) {
      float bb = fb2[n];
      #pragma unroll
      for (int r = 0; r < 4; ++r) {
        float v = s_red[0][r][n] + s_red[1][r][n] + s_red[2][r][n] + s_red[3][r][n] + bb;
        V_bf[(size_t)(r0 + r) * 256 + n] = bf16_rne(v);
      }
    }
  } else {
    const int i  = blockIdx.x - 256;
    const int b  = i >> 7;
    const int og = i & 127;
    const int ol = threadIdx.x >> 8;
    const int j  = threadIdx.x & 255;
    const int o  = og * 4 + ol;
    float c0 = kw1[3 * 256 + j] - kw1[6 * 256 + j];
    float c1 = kw1[4 * 256 + j] - kw1[7 * 256 + j];
    float c2 = kw1[5 * 256 + j] - kw1[8 * 256 + j];
    const float* p = pos_obs + ((size_t)(b * NO + o)) * 3;
    AO_bf[(size_t)(b * NO + o) * 256 + j] =
        bf16_rne(fmaf(p[0], c0, fmaf(p[1], c1, p[2] * c2)));
  }
}

// ---------------------------------------------------------------------------
// Fused attention + out_proj. QT=2, 512 threads (8 waves).
// __launch_bounds__(512, 2): LDS caps at 2 blocks/CU anyway; give the
// register allocator the full 256-VGPR budget for AO prefetch ILP.
__global__ __launch_bounds__(512, 2) void attn_fused(
    const unsigned short* __restrict__ V_bf,   // (B*NO, 256) bf16
    const unsigned short* __restrict__ AO_bf,  // (B*NO, 256) bf16
    const float* __restrict__ kw1,       // (9, 256)
    const float* __restrict__ kb1,       // (256)
    const float* __restrict__ kw2,       // (256, 8)
    const float* __restrict__ kb2,       // (8)
    const float* __restrict__ log_sigma, // (8)
    const float* __restrict__ pos_obs,   // (B*NO, 3)
    const float* __restrict__ pos_query, // (B*NQ, 3)
    const float* __restrict__ ow, const float* __restrict__ obias,
    const float* __restrict__ vw, const float* __restrict__ vbias,
    float* __restrict__ out)
{
  __shared__ float s_logits[2][8 * LPAD];        // 33,024 B
  __shared__ __align__(16) char poolA[33024];    // Bfrags 16,384 | redC 16xRP2 | s_pred
  __shared__ __align__(16) char poolB[4096];     // aq 2K | s_hv 4K
  __shared__ float s_sum[2][8];
  __shared__ float s_invs2[8];
  __shared__ float s_kb2v[8];

  short8* Bhi    = (short8*)poolA;               // [kstep*64 + lane]
  short8* Blo    = (short8*)(poolA + 8192);
  float*  s_redC = (float*)poolA;                // [16][RP2]
  float*  s_pred = (float*)poolA;                // [ks][mode][q][128]
  float*  s_aq   = (float*)poolB;                // [q*256 + j]
  float*  s_hv   = (float*)poolB;                // [(q*2+mode)*256 + hd]

  const int t   = threadIdx.x;
  const int bq0 = blockIdx.x * 2;
  const int b   = bq0 >> 9;

  // ---- prologue -----------------------------------------------------------
  float pqx[2], pqy[2], pqz[2];
  #pragma unroll
  for (int q = 0; q < 2; ++q) {
    pqx[q] = pos_query[(bq0 + q) * 3 + 0];
    pqy[q] = pos_query[(bq0 + q) * 3 + 1];
    pqz[q] = pos_query[(bq0 + q) * 3 + 2];
  }
  // aq[q][j]
  {
    const int q = t >> 8, j = t & 255;
    float c0 = kw1[0 * 256 + j] + kw1[6 * 256 + j];
    float c1 = kw1[1 * 256 + j] + kw1[7 * 256 + j];
    float c2 = kw1[2 * 256 + j] + kw1[8 * 256 + j];
    s_aq[q * 256 + j] =
        fmaf(pqx[q], c0, fmaf(pqy[q], c1, fmaf(pqz[q], c2, kb1[j])));
  }
  // B fragments: kw2 split bf16 hi/lo
  {
    const int kstep = t >> 6, lane = t & 63;
    const int nh = lane & 15;
    const int kb_ = kstep * 32 + ((lane >> 4) & 3) * 8;
    short8 hi8, lo8;
    #pragma unroll
    for (int i = 0; i < 8; ++i) {
      float v = (nh < 8) ? kw2[(kb_ + i) * 8 + nh] : 0.f;
      unsigned short h = bf16_rne(v);
      hi8[i] = (short)h;
      lo8[i] = (short)bf16_rne(v - bf16_to_f32(h));
    }
    Bhi[kstep * 64 + lane] = hi8;
    Blo[kstep * 64 + lane] = lo8;
  }
  if (t < 8) {
    float s = __expf(log_sigma[t]);
    s_invs2[t] = 1.0f / (s * s + 1e-6f);
    s_kb2v[t]  = kb2[t];
  }
  __syncthreads();                                           // B1

  // ---- rbf prefill by ALL threads (native transcendentals), o = t ---------
  {
    const int o = t;
    const float* p = pos_obs + (size_t)(b * NO + o) * 3;
    float px = p[0], py = p[1], pz = p[2];
    float d2q[2];
    #pragma unroll
    for (int q = 0; q < 2; ++q) {
      float r0 = pqx[q] - px, r1 = pqy[q] - py, r2 = pqz[q] - pz;
      d2q[q] = r0 * r0 + r1 * r1 + r2 * r2;
    }
    #pragma unroll
    for (int h = 0; h < 8; ++h) {
      float inv = s_invs2[h];
      float kbv = s_kb2v[h];
      s_logits[0][h * LPAD + o] = __logf(__expf(-d2q[0] * inv) + 1e-8f) + kbv;
      s_logits[1][h * LPAD + o] = __logf(__expf(-d2q[1] * inv) + 1e-8f) + kbv;
    }
  }

  // ---- phase 1: MFMA delta with AO double-buffer --------------------------
  {
    const int wave = t >> 6, lane = t & 63;
    const int quad = lane >> 4, mrow = lane & 15;
    const int tb   = wave * 4;                   // 4 o-tiles per wave, both q
    f32x4 C[2][4];
    #pragma unroll
    for (int q = 0; q < 2; ++q)
      #pragma unroll
      for (int jt = 0; jt < 4; ++jt) C[q][jt] = (f32x4){0.f, 0.f, 0.f, 0.f};

    const unsigned short* aob[4];
    #pragma unroll
    for (int jt = 0; jt < 4; ++jt)
      aob[jt] = AO_bf + ((size_t)(b * NO + (tb + jt) * 16 + mrow) << 8) + quad * 8;

    int4 u_cur[4];
    #pragma unroll
    for (int jt = 0; jt < 4; ++jt) u_cur[jt] = *(const int4*)(aob[jt]);

    for (int kstep = 0; kstep < 8; ++kstep) {
      int4 u_nxt[4];
      if (kstep < 7) {
        #pragma unroll
        for (int jt = 0; jt < 4; ++jt)
          u_nxt[jt] = *(const int4*)(aob[jt] + (kstep + 1) * 32);
      }
      const int koff = kstep * 32 + quad * 8;
      const v2f* aqp0 = (const v2f*)(s_aq + koff);
      const v2f* aqp1 = (const v2f*)(s_aq + 256 + koff);
      v2f aq0[4], aq1[4];
      #pragma unroll
      for (int i = 0; i < 4; ++i) { aq0[i] = aqp0[i]; aq1[i] = aqp1[i]; }
      short8 bhi = Bhi[kstep * 64 + lane];
      short8 blo = Blo[kstep * 64 + lane];
      #pragma unroll
      for (int jt = 0; jt < 4; ++jt) {
        int4 u = u_cur[jt];
        v2f ao[4];
        ao[0] = unpk_bf2((unsigned)u.x); ao[1] = unpk_bf2((unsigned)u.y);
        ao[2] = unpk_bf2((unsigned)u.z); ao[3] = unpk_bf2((unsigned)u.w);
        v2f z = splat2(0.f);
        int4 af0, af1;
        {
          v2f h0 = max2(aq0[0] + ao[0], z), h1 = max2(aq0[1] + ao[1], z);
          v2f h2 = max2(aq0[2] + ao[2], z), h3 = max2(aq0[3] + ao[3], z);
          af0.x = (int)pack_bf2(h0.x, h0.y); af0.y = (int)pack_bf2(h1.x, h1.y);
          af0.z = (int)pack_bf2(h2.x, h2.y); af0.w = (int)pack_bf2(h3.x, h3.y);
        }
        {
          v2f h0 = max2(aq1[0] + ao[0], z), h1 = max2(aq1[1] + ao[1], z);
          v2f h2 = max2(aq1[2] + ao[2], z), h3 = max2(aq1[3] + ao[3], z);
          af1.x = (int)pack_bf2(h0.x, h0.y); af1.y = (int)pack_bf2(h1.x, h1.y);
          af1.z = (int)pack_bf2(h2.x, h2.y); af1.w = (int)pack_bf2(h3.x, h3.y);
        }
        short8 a0 = __builtin_bit_cast(short8, af0);
        short8 a1 = __builtin_bit_cast(short8, af1);
        C[0][jt] = __builtin_amdgcn_mfma_f32_16x16x32_bf16(a0, bhi, C[0][jt], 0, 0, 0);
        C[0][jt] = __builtin_amdgcn_mfma_f32_16x16x32_bf16(a0, blo, C[0][jt], 0, 0, 0);
        C[1][jt] = __builtin_amdgcn_mfma_f32_16x16x32_bf16(a1, bhi, C[1][jt], 0, 0, 0);
        C[1][jt] = __builtin_amdgcn_mfma_f32_16x16x32_bf16(a1, blo, C[1][jt], 0, 0, 0);
      }
      #pragma unroll
      for (int jt = 0; jt < 4; ++jt) u_cur[jt] = u_nxt[jt];
    }
    __syncthreads();   // prefill complete before += epilogue        // B2

    // epilogue: lane holds D[n=h][m=quad*4+r]; add delta into prefilled rbf
    const int h = lane & 15;
    if (h < 8) {
      #pragma unroll
      for (int q = 0; q < 2; ++q)
        #pragma unroll
        for (int jt = 0; jt < 4; ++jt) {
          const int ob = (tb + jt) * 16 + quad * 4;
          #pragma unroll
          for (int r = 0; r < 4; ++r)
            s_logits[q][h * LPAD + ob + r] += C[q][jt][r];
        }
    }
  }
  __syncthreads();                                           // B3

  // ---- phase 2: softmax (8 waves x 2 (q,h) rows), native exp --------------
  {
    const int wave = t >> 6, lane = t & 63;
    #pragma unroll
    for (int cc = 0; cc < 2; ++cc) {
      const int c = wave * 2 + cc;
      const int q = c >> 3, h = c & 7;
      float* pl = &s_logits[q][h * LPAD];
      float l[8];
      float m = -1e30f;
      #pragma unroll
      for (int k = 0; k < 8; ++k) {
        l[k] = pl[k * 64 + lane];
        m = fmaxf(m, l[k]);
      }
      #pragma unroll
      for (int off = 32; off >= 1; off >>= 1) m = fmaxf(m, __shfl_xor(m, off, 64));
      float s = 0.f;
      #pragma unroll
      for (int k = 0; k < 8; ++k) {
        float p = __expf(l[k] - m);
        pl[k * 64 + lane] = p;
        s += p;
      }
      #pragma unroll
      for (int off = 32; off >= 1; off >>= 1) s += __shfl_xor(s, off, 64);
      if (lane == 0) s_sum[q][h] = s;
    }
  }
  __syncthreads();                                           // B4

  // ---- phase 3: PV + P V^2, 8 d per thread, uint4 V loads -----------------
  {
    const int q  = t >> 8;
    const int rr = t & 255;
    const int s  = rr >> 5;              // o-slice of 64
    const int h  = (rr >> 2) & 7;
    const int dg = rr & 3;               // d-octet
    const unsigned short* vb_ = V_bf + ((size_t)(b * NO) << 8) + h * 32 + dg * 8;
    const float* P = &s_logits[q][h * LPAD + s * 64];
    v2f s1[4], s2[4];
    #pragma unroll
    for (int i = 0; i < 4; ++i) { s1[i] = splat2(0.f); s2[i] = splat2(0.f); }
    const int o0 = s * 64;
    #pragma unroll 2
    for (int oi = 0; oi < 64; oi += 4) {
      float4 pv = *(const float4*)&P[oi];       // ds_read_b128 broadcast
      #pragma unroll
      for (int i = 0; i < 4; ++i) {
        const int o = o0 + oi + i;
        uint4 vv = *(const uint4*)(vb_ + ((size_t)o << 8));
        v2f p = splat2((&pv.x)[i]);
        v2f v0 = unpk_bf2(vv.x), v1 = unpk_bf2(vv.y);
        v2f v2 = unpk_bf2(vv.z), v3 = unpk_bf2(vv.w);
        s1[0] = fma2(p, v0, s1[0]); s1[1] = fma2(p, v1, s1[1]);
        s1[2] = fma2(p, v2, s1[2]); s1[3] = fma2(p, v3, s1[3]);
        v2f t0 = p * v0, t1 = p * v1, t2 = p * v2, t3 = p * v3;
        s2[0] = fma2(t0, v0, s2[0]); s2[1] = fma2(t1, v1, s2[1]);
        s2[2] = fma2(t2, v2, s2[2]); s2[3] = fma2(t3, v3, s2[3]);
      }
    }
    #pragma unroll
    for (int i = 0; i < 4; ++i) {
      s_redC[(2 * i + 0) * RP2 + t] = s1[i].x;
      s_redC[(2 * i + 1) * RP2 + t] = s1[i].y;
      s_redC[(8 + 2 * i + 0) * RP2 + t] = s2[i].x;
      s_redC[(8 + 2 * i + 1) * RP2 + t] = s2[i].y;
    }
  }
  __syncthreads();                                           // B5

  // ---- reduce 8 o-slices, both q in one pass -> s_hv ----------------------
  {
    const int q  = t >> 8;
    const int hd = t & 255;
    const int h  = hd >> 5, d = hd & 31;
    const int dgr = d >> 3, c = d & 7;
    float S1 = 0.f, S2 = 0.f;
    #pragma unroll
    for (int s = 0; s < 8; ++s) {
      const int col = q * 256 + s * 32 + h * 4 + dgr;
      S1 += s_redC[c * RP2 + col];
      S2 += s_redC[(8 + c) * RP2 + col];
    }
    float inv = 1.0f / s_sum[q][h];
    float m1 = S1 * inv;
    float va = fmaxf(S2 * inv - m1 * m1, 0.f);
    __syncthreads();                                         // B6 (aq dead)
    s_hv[(q * 2 + 0) * 256 + hd] = m1;
    s_hv[(q * 2 + 1) * 256 + hd] = va;
  }
  __syncthreads();                                           // B7

  // ---- phase 4: out_proj, k-split 2 ---------------------------------------
  {
    const int ks = t >> 8, mode = (t >> 7) & 1, n = t & 127;
    const float* W  = mode ? vw : ow;
    const float* X0 = s_hv + mode * 256;        // q0
    const float* X1 = s_hv + (2 + mode) * 256;  // q1
    float a0 = 0.f, a1 = 0.f;
    const int k0 = ks * 128;
    #pragma unroll 4
    for (int k = k0; k < k0 + 128; k += 4) {
      float4 x0 = *(const float4*)&X0[k];
      float4 x1 = *(const float4*)&X1[k];
      float w0 = W[(k + 0) * 128 + n];
      float w1 = W[(k + 1) * 128 + n];
      float w2 = W[(k + 2) * 128 + n];
      float w3 = W[(k + 3) * 128 + n];
      a0 = fmaf(x0.x, w0, a0); a1 = fmaf(x1.x, w0, a1);
      a0 = fmaf(x0.y, w1, a0); a1 = fmaf(x1.y, w1, a1);
      a0 = fmaf(x0.z, w2, a0); a1 = fmaf(x1.z, w2, a1);
      a0 = fmaf(x0.w, w3, a0); a1 = fmaf(x1.w, w3, a1);
    }
    __syncthreads();                            // redC dead; reuse as s_pred
    s_pred[((ks * 2 + mode) * 2 + 0) * 128 + n] = a0;
    s_pred[((ks * 2 + mode) * 2 + 1) * 128 + n] = a1;
  }
  __syncthreads();
  {
    const int q = t >> 8, mode = (t >> 7) & 1, n = t & 127;
    float v = s_pred[((0 * 2 + mode) * 2 + q) * 128 + n]
            + s_pred[((1 * 2 + mode) * 2 + q) * 128 + n]
            + (mode ? vbias[n] : obias[n]);
    if (mode) v = softplus_f(v);
    out[(size_t)mode * (NB * NQ * OUT_DIM) + (size_t)(bq0 + q) * OUT_DIM + n] = v;
  }
}

// ---------------------------------------------------------------------------
extern "C" void kernel_launch(void* const* d_in, const int* in_sizes, int n_in,
                              void* d_out, int out_size, void* d_ws, size_t ws_size,
                              hipStream_t stream)
{
  const float* h_obs     = (const float*)d_in[0];
  const float* pos_obs   = (const float*)d_in[1];
  const float* pos_query = (const float*)d_in[2];
  const float* fw1       = (const float*)d_in[3];
  const float* fb1       = (const float*)d_in[4];
  const float* fw2       = (const float*)d_in[5];
  const float* fb2       = (const float*)d_in[6];
  const float* log_sigma = (const float*)d_in[7];
  const float* kw1       = (const float*)d_in[8];
  const float* kb1       = (const float*)d_in[9];
  const float* kw2       = (const float*)d_in[10];
  const float* kb2       = (const float*)d_in[11];
  const float* ow        = (const float*)d_in[12];
  const float* ob        = (const float*)d_in[13];
  const float* vw        = (const float*)d_in[14];
  const float* vb        = (const float*)d_in[15];

  float* out = (float*)d_out;
  unsigned short* ws = (unsigned short*)d_ws;

  unsigned short* V_bf  = ws;            // 262144 ushort = 512 KB
  unsigned short* AO_bf = ws + 262144;

  prep_kernel<<<512, 1024, 0, stream>>>(h_obs, fw1, fb1, fw2, fb2,
                                        pos_obs, kw1, V_bf, AO_bf);
  attn_fused<<<NB * NQ / 2, 512, 0, stream>>>(V_bf, AO_bf, kw1, kb1, kw2, kb2,
                                              log_sigma, pos_obs, pos_query,
                                              ow, ob, vw, vb, out);
}